// Round 1
// baseline (1178.666 us; speedup 1.0000x reference)
//
#include <hip/hip_runtime.h>
#include <hip/hip_bf16.h>

#define BATCH 4096
#define CIN   256
#define COUT  256
#define NCELL 81
#define ND    17

typedef short bf16x8 __attribute__((ext_vector_type(8)));
typedef float f32x4  __attribute__((ext_vector_type(4)));

__device__ __forceinline__ unsigned short f2b(float f) {
    union { float f; unsigned int u; } v; v.f = f;
    unsigned int u = v.u;
    return (unsigned short)((u + 0x7fffu + ((u >> 16) & 1u)) >> 16);  // RNE
}

// Convert weights fp32 [17,256,256] -> bf16 (same layout) into d_ws.
__global__ void prep_weights(const float* __restrict__ w,
                             unsigned short* __restrict__ wb, int n) {
    int i = (blockIdx.x * blockDim.x + threadIdx.x) * 4;
    if (i + 3 < n) {
        float4 f = *(const float4*)(w + i);
        ushort4 o;
        o.x = f2b(f.x); o.y = f2b(f.y); o.z = f2b(f.z); o.w = f2b(f.w);
        *(ushort4*)(wb + i) = o;
    }
}

// Block: 16 batches x one board row (9 cells) x all 256 C_OUT.
// 16 waves; wave w owns o in [w*16, w*16+16). K streamed in chunks of 64.
__global__ __launch_bounds__(1024, 4) void diag_kernel(
    const float* __restrict__ in, const unsigned short* __restrict__ wb,
    const float* __restrict__ bias, float* __restrict__ out)
{
    // LDS: xs[9][16][72] bf16 (20736 B) aliased with outst[16][577] f32 (36928 B)
    __shared__ __align__(16) char ldsbuf[36928];
    unsigned short* xs   = (unsigned short*)ldsbuf;
    float*          outst = (float*)ldsbuf;

    const int t   = threadIdx.x;
    const int ln  = t & 63;
    const int w   = t >> 6;          // wave 0..15
    const int bt  = blockIdx.x / 9;
    const int row = blockIdx.x % 9;  // board row i; cells row*9 .. row*9+8, diag d = row + j
    const int b0  = bt * 16;

    const int sb = t >> 6;           // staging batch 0..15
    const int sc = t & 63;           // staging channel 0..63

    const float* src = in + ((size_t)(b0 + sb) * CIN + sc) * NCELL + row * 9;

    f32x4 acc[9];
#pragma unroll
    for (int j = 0; j < 9; ++j) acc[j] = (f32x4)(0.0f);

    const int m  = ln & 15;          // fragment row/col index
    const int kq = ln >> 4;          // 0..3

    for (int kc = 0; kc < 4; ++kc) {
        __syncthreads();
        // ---- stage in[b0:16, kc*64:+64, row*9:+9] -> bf16 LDS xs[j][b][c]
        const float* s = src + (size_t)kc * 64 * NCELL;
        unsigned short* xw = xs + sb * 72 + sc;
#pragma unroll
        for (int e = 0; e < 9; ++e)
            xw[e * (16 * 72)] = f2b(s[e]);
        __syncthreads();

        // ---- MFMA: per cell j, 2 K-subchunks of 32
#pragma unroll
        for (int j = 0; j < 9; ++j) {
            const unsigned short* xr = xs + (j * 16 + m) * 72 + kq * 8;
            bf16x8 bf0 = *(const bf16x8*)xr;
            bf16x8 bf1 = *(const bf16x8*)(xr + 32);
            const unsigned short* wp =
                wb + ((size_t)(row + j) * COUT + w * 16 + m) * CIN + kc * 64 + kq * 8;
            bf16x8 af0 = *(const bf16x8*)wp;
            bf16x8 af1 = *(const bf16x8*)(wp + 32);
            acc[j] = __builtin_amdgcn_mfma_f32_16x16x32_bf16(af0, bf0, acc[j], 0, 0, 0);
            acc[j] = __builtin_amdgcn_mfma_f32_16x16x32_bf16(af1, bf1, acc[j], 0, 0, 0);
        }
    }

    // ---- epilogue: 4 phases of 64 C_OUT each; assemble rows in LDS, flush 36 B/row
    for (int p = 0; p < 4; ++p) {
        __syncthreads();
        if ((w >> 2) == p) {
            const int olocal = (w & 3) * 16 + kq * 4;   // 0..63 (+r)
#pragma unroll
            for (int j = 0; j < 9; ++j) {
                f32x4 bb = *(const f32x4*)(bias + (row + j) * COUT + p * 64 + olocal);
#pragma unroll
                for (int r = 0; r < 4; ++r)
                    outst[m * 577 + (olocal + r) * 9 + j] = acc[j][r] + bb[r];
            }
        }
        __syncthreads();
        {
            const int fb = t >> 6;   // 0..15
            const int fo = t & 63;   // 0..63
            const float* sp = outst + fb * 577 + fo * 9;
            float* dp = out + ((size_t)(b0 + fb) * COUT + p * 64 + fo) * NCELL + row * 9;
#pragma unroll
            for (int e = 0; e < 9; ++e) dp[e] = sp[e];
        }
    }
}

extern "C" void kernel_launch(void* const* d_in, const int* in_sizes, int n_in,
                              void* d_out, int out_size, void* d_ws, size_t ws_size,
                              hipStream_t stream) {
    const float* in   = (const float*)d_in[0];
    const float* wts  = (const float*)d_in[1];
    const float* bias = (const float*)d_in[2];
    float* out        = (float*)d_out;
    unsigned short* wb = (unsigned short*)d_ws;   // bf16 weights scratch (2.2 MB)

    const int nw = ND * COUT * CIN;               // 1,114,112 (divisible by 1024)
    prep_weights<<<nw / 4 / 256, 256, 0, stream>>>(wts, wb, nw);
    diag_kernel<<<(BATCH / 16) * 9, 1024, 0, stream>>>(in, wb, bias, out);
}